// Round 1
// baseline (2209.534 us; speedup 1.0000x reference)
//
#include <hip/hip_runtime.h>

typedef short short8  __attribute__((ext_vector_type(8)));
typedef short short4v __attribute__((ext_vector_type(4)));
typedef float f32x4   __attribute__((ext_vector_type(4)));

// ---------- helpers ----------
__device__ __forceinline__ short f2bf(float f) {
  union { float f; unsigned u; } v; v.f = f;
  unsigned r = v.u + 0x7fffu + ((v.u >> 16) & 1u);  // round-to-nearest-even
  return (short)(r >> 16);
}

__device__ __forceinline__ void gload_lds16(const short* g, short* l) {
  __builtin_amdgcn_global_load_lds(
      (const __attribute__((address_space(1))) void*)g,
      (__attribute__((address_space(3))) void*)l, 16, 0, 0);
}

// ---------- bf16 MFMA GEMM: C[M,N] = A[M,K] @ B[K,N], B given as Bt[N,K] ----------
// EPI 0: store f32, no bias. EPI 1: +bias, relu, store f32. EPI 2: +bias, BN, relu, store bf16.
template <int EPI>
__launch_bounds__(256)
__global__ void gemm_bt(const short* __restrict__ A, const short* __restrict__ Bt,
                        float* __restrict__ Cf, short* __restrict__ Cb,
                        int Mpad, int N, int K,
                        const float* __restrict__ bias,
                        const float* __restrict__ gamma, const float* __restrict__ beta,
                        const float* __restrict__ mean, const float* __restrict__ var) {
  __shared__ short lA[128 * 32];
  __shared__ short lB[128 * 32];
  const int t = threadIdx.x;
  const int lane = t & 63;
  const int wave = t >> 6;
  const int wr = (wave >> 1) * 64;   // wave row offset in tile
  const int wc = (wave & 1) * 64;    // wave col offset in tile
  const int tileM = blockIdx.y * 128;
  const int tileN = blockIdx.x * 128;

  f32x4 acc[4][4] = {};

  // staging: 256 lanes x 16B = 4KB covers 64 rows of [row][32] bf16; 2 chunks per tile
  const short* aSrc = A  + (size_t)(tileM + (t >> 2)) * K + (t & 3) * 8;
  const short* bSrc = Bt + (size_t)(tileN + (t >> 2)) * K + (t & 3) * 8;
  const size_t rowStep = (size_t)64 * K;
  short* lAdst = lA + t * 8;   // linear: wave-uniform base + lane*16B
  short* lBdst = lB + t * 8;

  const int fr = lane & 15;
  const int kg = (lane >> 4) * 8;

  for (int k0 = 0; k0 < K; k0 += 32) {
    gload_lds16(aSrc + k0,           lAdst);
    gload_lds16(aSrc + rowStep + k0, lAdst + 64 * 32);
    gload_lds16(bSrc + k0,           lBdst);
    gload_lds16(bSrc + rowStep + k0, lBdst + 64 * 32);
    __syncthreads();   // compiler emits vmcnt(0) drain before barrier
    short8 af[4], bf[4];
#pragma unroll
    for (int m = 0; m < 4; ++m)
      af[m] = *(const short8*)(lA + (wr + m * 16 + fr) * 32 + kg);
#pragma unroll
    for (int n = 0; n < 4; ++n)
      bf[n] = *(const short8*)(lB + (wc + n * 16 + fr) * 32 + kg);
#pragma unroll
    for (int m = 0; m < 4; ++m)
#pragma unroll
      for (int n = 0; n < 4; ++n)
        acc[m][n] = __builtin_amdgcn_mfma_f32_16x16x32_bf16(af[m], bf[n], acc[m][n], 0, 0, 0);
    __syncthreads();
  }

  // epilogue: C/D layout col=lane&15, row=(lane>>4)*4+reg  [m89-verified]
  const int rg = (lane >> 4) * 4;
#pragma unroll
  for (int m = 0; m < 4; ++m) {
#pragma unroll
    for (int n = 0; n < 4; ++n) {
      const int col = tileN + wc + n * 16 + fr;
      const float bi = (EPI >= 1) ? bias[col] : 0.f;
      float sc = 1.f, sh = 0.f;
      if (EPI == 2) {
        sc = rsqrtf(var[col] + 1e-5f) * gamma[col];
        sh = beta[col] - mean[col] * sc;
      }
#pragma unroll
      for (int r = 0; r < 4; ++r) {
        const int row = tileM + wr + m * 16 + rg + r;
        float v = acc[m][n][r] + bi;
        if (EPI == 2) v = v * sc + sh;
        if (EPI >= 1) v = fmaxf(v, 0.f);
        if (EPI == 2) Cb[(size_t)row * N + col] = f2bf(v);
        else          Cf[(size_t)row * N + col] = v;
      }
    }
  }
}

// ---------- conversions ----------
__global__ void conv_x_bf(const float* __restrict__ x, short* __restrict__ xb,
                          long nReal, long nTot) {
  long i = ((long)blockIdx.x * blockDim.x + threadIdx.x) * 4;
  if (i >= nTot) return;
  short4v o;
  if (i < nReal) {
    o[0] = f2bf(x[i + 0]); o[1] = f2bf(x[i + 1]);
    o[2] = f2bf(x[i + 2]); o[3] = f2bf(x[i + 3]);
  } else {
    o[0] = o[1] = o[2] = o[3] = 0;   // zero padding rows
  }
  *(short4v*)(xb + i) = o;
}

__global__ void conv_w_t(const float* __restrict__ W, short* __restrict__ Wt, int K, int N) {
  int idx = blockIdx.x * blockDim.x + threadIdx.x;
  if (idx >= K * N) return;
  int k = idx / N, n = idx - k * N;
  Wt[(size_t)n * K + k] = f2bf(W[idx]);
}

// ---------- scatter aggregation (one wave per edge, 512 floats) ----------
__global__ void agg_atomic(const float* __restrict__ Y, float* __restrict__ agg,
                           const int* __restrict__ src, const int* __restrict__ dst, int nE) {
  int e = blockIdx.x * 4 + (threadIdx.x >> 6);
  if (e >= nE) return;
  int lane = threadIdx.x & 63;
  const float* yr = Y + (size_t)src[e] * 512;
  float* ar = agg + (size_t)dst[e] * 512;
#pragma unroll
  for (int i = 0; i < 8; ++i)
    atomicAdd(ar + lane + i * 64, yr[lane + i * 64]);
}

// ---------- post-agg finalize ----------
// h = relu(BN(Y + agg + bias)) -> bf16   (layer 1 between-GEMM step)
__global__ void fin_bn(const float* __restrict__ Y, const float* __restrict__ A,
                       const float* __restrict__ b, const float* __restrict__ gm,
                       const float* __restrict__ bt, const float* __restrict__ mn,
                       const float* __restrict__ vr, short* __restrict__ out, long total) {
  long i = ((long)blockIdx.x * blockDim.x + threadIdx.x) * 4;
  if (i >= total) return;
  int d = (int)(i & 511);
  short4v o;
#pragma unroll
  for (int j = 0; j < 4; ++j) {
    float t = Y[i + j] + A[i + j] + b[d + j];
    float sc = rsqrtf(vr[d + j] + 1e-5f) * gm[d + j];
    t = (t - mn[d + j]) * sc + bt[d + j];
    o[j] = f2bf(fmaxf(t, 0.f));
  }
  *(short4v*)(out + i) = o;
}

// h2pre = bf16(Y + agg)   (layer 2: bias/BN applied inside next GEMM epilogue)
__global__ void fin_add(const float* __restrict__ Y, const float* __restrict__ A,
                        short* __restrict__ out, long total) {
  long i = ((long)blockIdx.x * blockDim.x + threadIdx.x) * 4;
  if (i >= total) return;
  short4v o;
#pragma unroll
  for (int j = 0; j < 4; ++j) o[j] = f2bf(Y[i + j] + A[i + j]);
  *(short4v*)(out + i) = o;
}

// ---------- final projection [M,512] @ [512,2] + bout ----------
__global__ void out_proj(const float* __restrict__ H, const float* __restrict__ Wout,
                         const float* __restrict__ bout, float* __restrict__ out, int M) {
  int row = blockIdx.x * 4 + (threadIdx.x >> 6);
  if (row >= M) return;
  int lane = threadIdx.x & 63;
  const float* hr = H + (size_t)row * 512;
  float s0 = 0.f, s1 = 0.f;
#pragma unroll
  for (int i = 0; i < 8; ++i) {
    float h = hr[lane + i * 64];
    s0 += h * Wout[(lane + i * 64) * 2 + 0];
    s1 += h * Wout[(lane + i * 64) * 2 + 1];
  }
#pragma unroll
  for (int off = 32; off > 0; off >>= 1) {
    s0 += __shfl_down(s0, off);
    s1 += __shfl_down(s1, off);
  }
  if (lane == 0) {
    out[row * 2 + 0] = s0 + bout[0];
    out[row * 2 + 1] = s1 + bout[1];
  }
}

extern "C" void kernel_launch(void* const* d_in, const int* in_sizes, int n_in,
                              void* d_out, int out_size, void* d_ws, size_t ws_size,
                              hipStream_t stream) {
  const float* x   = (const float*)d_in[0];
  const int*   ei  = (const int*)d_in[1];
  const float* W1a = (const float*)d_in[2];
  const float* b1a = (const float*)d_in[3];
  const float* g1  = (const float*)d_in[4];
  const float* be1 = (const float*)d_in[5];
  const float* m1  = (const float*)d_in[6];
  const float* v1  = (const float*)d_in[7];
  const float* W1b = (const float*)d_in[8];
  const float* b1b = (const float*)d_in[9];
  const float* W2a = (const float*)d_in[10];
  const float* b2a = (const float*)d_in[11];
  const float* g2  = (const float*)d_in[12];
  const float* be2 = (const float*)d_in[13];
  const float* m2  = (const float*)d_in[14];
  const float* v2  = (const float*)d_in[15];
  const float* W2b = (const float*)d_in[16];
  const float* b2b = (const float*)d_in[17];
  const float* Wo  = (const float*)d_in[18];
  const float* bo  = (const float*)d_in[19];

  const int DH   = in_sizes[3];            // 512
  const int DIN  = in_sizes[2] / DH;       // 768
  const int NN   = in_sizes[0] / DIN;      // 50000
  const int nE   = in_sizes[1] / 2;        // 500000
  const int Mpad = (NN + 127) & ~127;      // 50048

  char* ws = (char*)d_ws;
  short* XB = (short*)ws;                  // [Mpad,DIN] bf16; reused as GEMM3 bf16 output
  size_t off = (size_t)Mpad * DIN * 2;
  short* W1aT = (short*)(ws + off); off += (size_t)DH * DIN * 2;
  short* W1bT = (short*)(ws + off); off += (size_t)DH * DH * 2;
  short* W2aT = (short*)(ws + off); off += (size_t)DH * DH * 2;
  short* W2bT = (short*)(ws + off); off += (size_t)DH * DH * 2;
  off = (off + 255) & ~(size_t)255;
  float* B1 = (float*)(ws + off); off += (size_t)Mpad * DH * 4;   // f32 activations
  float* B2 = (float*)(ws + off); off += (size_t)Mpad * DH * 4;   // aggregation accumulator
  short* B3 = (short*)(ws + off); off += (size_t)Mpad * DH * 2;   // bf16 activations

  const int* srcI = ei;
  const int* dstI = ei + nE;

  const long nTot = (long)Mpad * DIN, nReal = (long)NN * DIN;
  const long tot  = (long)Mpad * DH;

  // 0. dtype conversions
  conv_x_bf<<<(int)((nTot / 4 + 255) / 256), 256, 0, stream>>>(x, XB, nReal, nTot);
  conv_w_t<<<(DIN * DH + 255) / 256, 256, 0, stream>>>(W1a, W1aT, DIN, DH);
  conv_w_t<<<(DH * DH + 255) / 256, 256, 0, stream>>>(W1b, W1bT, DH, DH);
  conv_w_t<<<(DH * DH + 255) / 256, 256, 0, stream>>>(W2a, W2aT, DH, DH);
  conv_w_t<<<(DH * DH + 255) / 256, 256, 0, stream>>>(W2b, W2bT, DH, DH);

  dim3 gg(DH / 128, Mpad / 128);

  // 1. Y1 = X @ W1a  (no bias — aggregation commutes with the linear map)
  gemm_bt<0><<<gg, 256, 0, stream>>>(XB, W1aT, B1, nullptr, Mpad, DH, DIN,
                                     nullptr, nullptr, nullptr, nullptr, nullptr);
  // 2. agg1 = segment_sum(Y1[src], dst)  at 512 dims
  hipMemsetAsync(B2, 0, (size_t)Mpad * DH * 4, stream);
  agg_atomic<<<(nE + 3) / 4, 256, 0, stream>>>(B1, B2, srcI, dstI, nE);
  // 3. h1a = relu(BN(Y1 + agg1 + b1a)) -> bf16
  fin_bn<<<(int)((tot / 4 + 255) / 256), 256, 0, stream>>>(B1, B2, b1a, g1, be1, m1, v1, B3, tot);
  // 4. h1 = relu(h1a @ W1b + b1b) -> f32
  gemm_bt<1><<<gg, 256, 0, stream>>>(B3, W1bT, B1, nullptr, Mpad, DH, DH,
                                     b1b, nullptr, nullptr, nullptr, nullptr);
  // 5. agg2 = segment_sum(h1[src], dst)
  hipMemsetAsync(B2, 0, (size_t)Mpad * DH * 4, stream);
  agg_atomic<<<(nE + 3) / 4, 256, 0, stream>>>(B1, B2, srcI, dstI, nE);
  // 6. h2pre = bf16(h1 + agg2)
  fin_add<<<(int)((tot / 4 + 255) / 256), 256, 0, stream>>>(B1, B2, B3, tot);
  // 7. h2a = relu(BN(h2pre @ W2a + b2a)) -> bf16 (into XB region, X is dead)
  gemm_bt<2><<<gg, 256, 0, stream>>>(B3, W2aT, nullptr, XB, Mpad, DH, DH,
                                     b2a, g2, be2, m2, v2);
  // 8. h2 = relu(h2a @ W2b + b2b) -> f32
  gemm_bt<1><<<gg, 256, 0, stream>>>(XB, W2bT, B1, nullptr, Mpad, DH, DH,
                                     b2b, nullptr, nullptr, nullptr, nullptr);
  // 9. out = h2 @ Wout + bout
  out_proj<<<(NN + 3) / 4, 256, 0, stream>>>(B1, Wo, bo, (float*)d_out, NN);
}

// Round 3
// 971.574 us; speedup vs baseline: 2.2742x; 2.2742x over previous
//
#include <hip/hip_runtime.h>

typedef short short8  __attribute__((ext_vector_type(8)));
typedef short short4v __attribute__((ext_vector_type(4)));
typedef float f32x4   __attribute__((ext_vector_type(4)));

// ---------- helpers ----------
__device__ __forceinline__ short f2bf(float f) {
  union { float f; unsigned u; } v; v.f = f;
  unsigned r = v.u + 0x7fffu + ((v.u >> 16) & 1u);  // round-to-nearest-even
  return (short)(r >> 16);
}

__device__ __forceinline__ void gload_lds16(const short* g, short* l) {
  __builtin_amdgcn_global_load_lds(
      (const __attribute__((address_space(1))) void*)g,
      (__attribute__((address_space(3))) void*)l, 16, 0, 0);
}

// ---------- bf16 MFMA GEMM: C[M,N] = A[M,K] @ B[K,N], B given as Bt[N,K] ----------
// EPI 0: store f32, no bias. EPI 1: +bias, relu, store f32. EPI 2: +bias, BN, relu, store bf16.
template <int EPI>
__launch_bounds__(256)
__global__ void gemm_bt(const short* __restrict__ A, const short* __restrict__ Bt,
                        float* __restrict__ Cf, short* __restrict__ Cb,
                        int Mpad, int N, int K,
                        const float* __restrict__ bias,
                        const float* __restrict__ gamma, const float* __restrict__ beta,
                        const float* __restrict__ mean, const float* __restrict__ var) {
  __shared__ short lA[128 * 32];
  __shared__ short lB[128 * 32];
  const int t = threadIdx.x;
  const int lane = t & 63;
  const int wave = t >> 6;
  const int wr = (wave >> 1) * 64;   // wave row offset in tile
  const int wc = (wave & 1) * 64;    // wave col offset in tile
  const int tileM = blockIdx.y * 128;
  const int tileN = blockIdx.x * 128;

  f32x4 acc[4][4] = {};

  const short* aSrc = A  + (size_t)(tileM + (t >> 2)) * K + (t & 3) * 8;
  const short* bSrc = Bt + (size_t)(tileN + (t >> 2)) * K + (t & 3) * 8;
  const size_t rowStep = (size_t)64 * K;
  short* lAdst = lA + t * 8;   // linear: wave-uniform base + lane*16B
  short* lBdst = lB + t * 8;

  const int fr = lane & 15;
  const int kg = (lane >> 4) * 8;

  for (int k0 = 0; k0 < K; k0 += 32) {
    gload_lds16(aSrc + k0,           lAdst);
    gload_lds16(aSrc + rowStep + k0, lAdst + 64 * 32);
    gload_lds16(bSrc + k0,           lBdst);
    gload_lds16(bSrc + rowStep + k0, lBdst + 64 * 32);
    __syncthreads();
    short8 af[4], bf[4];
#pragma unroll
    for (int m = 0; m < 4; ++m)
      af[m] = *(const short8*)(lA + (wr + m * 16 + fr) * 32 + kg);
#pragma unroll
    for (int n = 0; n < 4; ++n)
      bf[n] = *(const short8*)(lB + (wc + n * 16 + fr) * 32 + kg);
#pragma unroll
    for (int m = 0; m < 4; ++m)
#pragma unroll
      for (int n = 0; n < 4; ++n)
        acc[m][n] = __builtin_amdgcn_mfma_f32_16x16x32_bf16(af[m], bf[n], acc[m][n], 0, 0, 0);
    __syncthreads();
  }

  const int rg = (lane >> 4) * 4;
#pragma unroll
  for (int m = 0; m < 4; ++m) {
#pragma unroll
    for (int n = 0; n < 4; ++n) {
      const int col = tileN + wc + n * 16 + fr;
      const float bi = (EPI >= 1) ? bias[col] : 0.f;
      float sc = 1.f, sh = 0.f;
      if (EPI == 2) {
        sc = rsqrtf(var[col] + 1e-5f) * gamma[col];
        sh = beta[col] - mean[col] * sc;
      }
#pragma unroll
      for (int r = 0; r < 4; ++r) {
        const int row = tileM + wr + m * 16 + rg + r;
        float v = acc[m][n][r] + bi;
        if (EPI == 2) v = v * sc + sh;
        if (EPI >= 1) v = fmaxf(v, 0.f);
        if (EPI == 2) Cb[(size_t)row * N + col] = f2bf(v);
        else          Cf[(size_t)row * N + col] = v;
      }
    }
  }
}

// ---------- conversions ----------
__global__ void conv_x_bf(const float* __restrict__ x, short* __restrict__ xb,
                          long nReal, long nTot) {
  long i = ((long)blockIdx.x * blockDim.x + threadIdx.x) * 4;
  if (i >= nTot) return;
  short4v o;
  if (i < nReal) {
    o[0] = f2bf(x[i + 0]); o[1] = f2bf(x[i + 1]);
    o[2] = f2bf(x[i + 2]); o[3] = f2bf(x[i + 3]);
  } else {
    o[0] = o[1] = o[2] = o[3] = 0;
  }
  *(short4v*)(xb + i) = o;
}

__global__ void conv_w_t(const float* __restrict__ W, short* __restrict__ Wt, int K, int N) {
  int idx = blockIdx.x * blockDim.x + threadIdx.x;
  if (idx >= K * N) return;
  int k = idx / N, n = idx - k * N;
  Wt[(size_t)n * K + k] = f2bf(W[idx]);
}

// ---------- CSR build ----------
__global__ void hist_deg(const int* __restrict__ dst, int* __restrict__ deg, int nE) {
  int e = blockIdx.x * blockDim.x + threadIdx.x;
  if (e < nE) atomicAdd(&deg[dst[e]], 1);
}

// single-block exclusive scan over n elements; writes rowstart[0..n] and cursor[0..n-1]
__global__ void scan_deg(const int* __restrict__ deg, int* __restrict__ rowstart,
                         int* __restrict__ cursor, int n) {
  __shared__ int wsum[16];
  __shared__ int carrySh;
  const int t = threadIdx.x;        // 1024 threads
  const int lane = t & 63, wv = t >> 6;
  int carry = 0;
  for (int base = 0; base < n; base += 8192) {
    int v[8]; int s = 0;
    const int i0 = base + t * 8;
#pragma unroll
    for (int j = 0; j < 8; ++j) {
      int idx = i0 + j;
      v[j] = (idx < n) ? deg[idx] : 0;
      s += v[j];
    }
    int ps = s;                      // inclusive wave scan
#pragma unroll
    for (int off = 1; off < 64; off <<= 1) {
      int u = __shfl_up(ps, off);
      if (lane >= off) ps += u;
    }
    if (lane == 63) wsum[wv] = ps;
    __syncthreads();
    if (wv == 0 && lane < 16) {
      int wsv = wsum[lane];
      int pw = wsv;
#pragma unroll
      for (int off = 1; off < 16; off <<= 1) {
        int u = __shfl_up(pw, off);
        if (lane >= off) pw += u;
      }
      wsum[lane] = pw - wsv;         // exclusive wave offset
      if (lane == 15) carrySh = pw;  // chunk total
    }
    __syncthreads();
    int run = carry + wsum[wv] + (ps - s);
#pragma unroll
    for (int j = 0; j < 8; ++j) {
      int idx = i0 + j;
      if (idx < n) { rowstart[idx] = run; cursor[idx] = run; }
      run += v[j];
    }
    carry += carrySh;
    __syncthreads();
  }
  if (t == 0) rowstart[n] = carry;
}

__global__ void fill_adj(const int* __restrict__ src, const int* __restrict__ dst,
                         int* __restrict__ cursor, int* __restrict__ adj, int nE) {
  int e = blockIdx.x * blockDim.x + threadIdx.x;
  if (e < nE) {
    int p = atomicAdd(&cursor[dst[e]], 1);
    adj[p] = src[e];
  }
}

// ---------- fused CSR aggregation + epilogue ----------
// out_i = f( Y_i + sum_{j in adj(i)} Y_j )
// EPI 1: f = bf16(relu(BN(. + bias)))   (between-GEMM, layer entry)
// EPI 0: f = bf16(.)                    (bias/BN folded into next GEMM epilogue)
template <int EPI>
__launch_bounds__(256)
__global__ void agg_csr(const float* __restrict__ Y,
                        const int* __restrict__ rowstart, const int* __restrict__ adj,
                        const float* __restrict__ bias, const float* __restrict__ gm,
                        const float* __restrict__ bt, const float* __restrict__ mn,
                        const float* __restrict__ vr,
                        short* __restrict__ out, int M) {
  const int node = blockIdx.x * 4 + (threadIdx.x >> 6);
  if (node >= M) return;
  const int lane = threadIdx.x & 63;
  const int d0 = lane * 8;

  const float* yr = Y + (size_t)node * 512 + d0;
  f32x4 a0 = *(const f32x4*)yr;
  f32x4 a1 = *(const f32x4*)(yr + 4);

  int s = rowstart[node];
  const int e = rowstart[node + 1];
  while (s < e) {
    const int cnt = min(e - s, 64);
    int myn = (lane < cnt) ? adj[s + lane] : 0;
    int i = 0;
    for (; i + 1 < cnt; i += 2) {          // 2-deep: 4 loads in flight
      int n0 = __shfl(myn, i);
      int n1 = __shfl(myn, i + 1);
      const float* r0 = Y + (size_t)n0 * 512 + d0;
      const float* r1 = Y + (size_t)n1 * 512 + d0;
      f32x4 b0 = *(const f32x4*)r0;
      f32x4 b1 = *(const f32x4*)(r0 + 4);
      f32x4 c0 = *(const f32x4*)r1;
      f32x4 c1 = *(const f32x4*)(r1 + 4);
      a0 += b0; a1 += b1; a0 += c0; a1 += c1;
    }
    if (i < cnt) {
      int n0 = __shfl(myn, i);
      const float* r0 = Y + (size_t)n0 * 512 + d0;
      a0 += *(const f32x4*)r0;
      a1 += *(const f32x4*)(r0 + 4);
    }
    s += cnt;
  }

  short8 o;
#pragma unroll
  for (int j = 0; j < 8; ++j) {
    float val = (j < 4) ? a0[j] : a1[j - 4];
    if (EPI == 1) {
      const int d = d0 + j;
      float sc = rsqrtf(vr[d] + 1e-5f) * gm[d];
      float tv = (val + bias[d] - mn[d]) * sc + bt[d];
      o[j] = f2bf(fmaxf(tv, 0.f));
    } else {
      o[j] = f2bf(val);
    }
  }
  *(short8*)(out + (size_t)node * 512 + d0) = o;
}

// ---------- final projection [M,512] @ [512,2] + bout ----------
__global__ void out_proj(const float* __restrict__ H, const float* __restrict__ Wout,
                         const float* __restrict__ bout, float* __restrict__ out, int M) {
  int row = blockIdx.x * 4 + (threadIdx.x >> 6);
  if (row >= M) return;
  int lane = threadIdx.x & 63;
  const float* hr = H + (size_t)row * 512;
  float s0 = 0.f, s1 = 0.f;
#pragma unroll
  for (int i = 0; i < 8; ++i) {
    float h = hr[lane + i * 64];
    s0 += h * Wout[(lane + i * 64) * 2 + 0];
    s1 += h * Wout[(lane + i * 64) * 2 + 1];
  }
#pragma unroll
  for (int off = 32; off > 0; off >>= 1) {
    s0 += __shfl_down(s0, off);
    s1 += __shfl_down(s1, off);
  }
  if (lane == 0) {
    out[row * 2 + 0] = s0 + bout[0];
    out[row * 2 + 1] = s1 + bout[1];
  }
}

extern "C" void kernel_launch(void* const* d_in, const int* in_sizes, int n_in,
                              void* d_out, int out_size, void* d_ws, size_t ws_size,
                              hipStream_t stream) {
  const float* x   = (const float*)d_in[0];
  const int*   ei  = (const int*)d_in[1];
  const float* W1a = (const float*)d_in[2];
  const float* b1a = (const float*)d_in[3];
  const float* g1  = (const float*)d_in[4];
  const float* be1 = (const float*)d_in[5];
  const float* m1  = (const float*)d_in[6];
  const float* v1  = (const float*)d_in[7];
  const float* W1b = (const float*)d_in[8];
  const float* b1b = (const float*)d_in[9];
  const float* W2a = (const float*)d_in[10];
  const float* b2a = (const float*)d_in[11];
  const float* g2  = (const float*)d_in[12];
  const float* be2 = (const float*)d_in[13];
  const float* m2  = (const float*)d_in[14];
  const float* v2  = (const float*)d_in[15];
  const float* W2b = (const float*)d_in[16];
  const float* b2b = (const float*)d_in[17];
  const float* Wo  = (const float*)d_in[18];
  const float* bo  = (const float*)d_in[19];

  const int DH   = in_sizes[3];            // 512
  const int DIN  = in_sizes[2] / DH;       // 768
  const int NN   = in_sizes[0] / DIN;      // 50000
  const int nE   = in_sizes[1] / 2;        // 500000
  const int Mpad = (NN + 127) & ~127;      // 50048

  char* ws = (char*)d_ws;
  short* XB = (short*)ws;                  // [Mpad,DIN] bf16; reused for GEMM3 bf16 output
  size_t off = (size_t)Mpad * DIN * 2;
  short* W1aT = (short*)(ws + off); off += (size_t)DH * DIN * 2;
  short* W1bT = (short*)(ws + off); off += (size_t)DH * DH * 2;
  short* W2aT = (short*)(ws + off); off += (size_t)DH * DH * 2;
  short* W2bT = (short*)(ws + off); off += (size_t)DH * DH * 2;
  off = (off + 255) & ~(size_t)255;
  float* B1 = (float*)(ws + off); off += (size_t)Mpad * DH * 4;   // f32 activations
  short* B3 = (short*)(ws + off); off += (size_t)Mpad * DH * 2;   // bf16 activations
  off = (off + 255) & ~(size_t)255;
  int* deg      = (int*)(ws + off); off += (size_t)(Mpad + 1) * 4;
  int* rowstart = (int*)(ws + off); off += (size_t)(Mpad + 1) * 4;
  int* cursor   = (int*)(ws + off); off += (size_t)(Mpad + 1) * 4;
  int* adj      = (int*)(ws + off); off += (size_t)nE * 4;

  const int* srcI = ei;
  const int* dstI = ei + nE;

  const long nTot = (long)Mpad * DIN, nReal = (long)NN * DIN;

  // 0. dtype conversions + CSR build (cheap; edges are 2 MB)
  conv_x_bf<<<(int)((nTot / 4 + 255) / 256), 256, 0, stream>>>(x, XB, nReal, nTot);
  conv_w_t<<<(DIN * DH + 255) / 256, 256, 0, stream>>>(W1a, W1aT, DIN, DH);
  conv_w_t<<<(DH * DH + 255) / 256, 256, 0, stream>>>(W1b, W1bT, DH, DH);
  conv_w_t<<<(DH * DH + 255) / 256, 256, 0, stream>>>(W2a, W2aT, DH, DH);
  conv_w_t<<<(DH * DH + 255) / 256, 256, 0, stream>>>(W2b, W2bT, DH, DH);
  hipMemsetAsync(deg, 0, (size_t)(Mpad + 1) * 4, stream);
  hist_deg<<<(nE + 255) / 256, 256, 0, stream>>>(dstI, deg, nE);
  scan_deg<<<1, 1024, 0, stream>>>(deg, rowstart, cursor, Mpad);
  fill_adj<<<(nE + 255) / 256, 256, 0, stream>>>(srcI, dstI, cursor, adj, nE);

  dim3 gg(DH / 128, Mpad / 128);
  const int aggGrid = Mpad / 4;

  // 1. Y1 = X @ W1a  (no bias — aggregation commutes with the linear map)
  gemm_bt<0><<<gg, 256, 0, stream>>>(XB, W1aT, B1, nullptr, Mpad, DH, DIN,
                                     nullptr, nullptr, nullptr, nullptr, nullptr);
  // 2+3. h1a = relu(BN(Y1_i + sum_j Y1_j + b1a)) -> bf16  (fused CSR gather)
  agg_csr<1><<<aggGrid, 256, 0, stream>>>(B1, rowstart, adj, b1a, g1, be1, m1, v1, B3, Mpad);
  // 4. h1 = relu(h1a @ W1b + b1b) -> f32
  gemm_bt<1><<<gg, 256, 0, stream>>>(B3, W1bT, B1, nullptr, Mpad, DH, DH,
                                     b1b, nullptr, nullptr, nullptr, nullptr);
  // 5+6. h2pre = bf16(h1_i + sum_j h1_j)
  agg_csr<0><<<aggGrid, 256, 0, stream>>>(B1, rowstart, adj, nullptr, nullptr, nullptr,
                                          nullptr, nullptr, B3, Mpad);
  // 7. h2a = relu(BN(h2pre @ W2a + b2a)) -> bf16 (into XB region, X is dead)
  gemm_bt<2><<<gg, 256, 0, stream>>>(B3, W2aT, nullptr, XB, Mpad, DH, DH,
                                     b2a, g2, be2, m2, v2);
  // 8. h2 = relu(h2a @ W2b + b2b) -> f32
  gemm_bt<1><<<gg, 256, 0, stream>>>(XB, W2bT, B1, nullptr, Mpad, DH, DH,
                                     b2b, nullptr, nullptr, nullptr, nullptr);
  // 9. out = h2 @ Wout + bout
  out_proj<<<(NN + 3) / 4, 256, 0, stream>>>(B1, Wo, bo, (float*)d_out, NN);
}

// Round 6
// 792.622 us; speedup vs baseline: 2.7876x; 1.2258x over previous
//
#include <hip/hip_runtime.h>

typedef short short8  __attribute__((ext_vector_type(8)));
typedef short short4v __attribute__((ext_vector_type(4)));
typedef float f32x4   __attribute__((ext_vector_type(4)));

// ---------- helpers ----------
__device__ __forceinline__ short f2bf(float f) {
  union { float f; unsigned u; } v; v.f = f;
  unsigned r = v.u + 0x7fffu + ((v.u >> 16) & 1u);  // round-to-nearest-even
  return (short)(r >> 16);
}

__device__ __forceinline__ float bf2f(short s) {
  union { unsigned u; float f; } v;
  v.u = ((unsigned)(unsigned short)s) << 16;
  return v.f;
}

__device__ __forceinline__ void gload_lds16(const short* g, short* l) {
  __builtin_amdgcn_global_load_lds(
      (const __attribute__((address_space(1))) void*)g,
      (__attribute__((address_space(3))) void*)l, 16, 0, 0);
}

// ---------- bf16 MFMA GEMM: C[M,N] = A[M,K] @ B[K,N], B as Bt[N,K], bf16 out ----------
template <bool BIAS, bool BN, bool RELU>
__launch_bounds__(256)
__global__ void gemm_bt(const short* __restrict__ A, const short* __restrict__ Bt,
                        short* __restrict__ C, int Mpad, int N, int K,
                        const float* __restrict__ bias,
                        const float* __restrict__ gamma, const float* __restrict__ beta,
                        const float* __restrict__ mean, const float* __restrict__ var) {
  __shared__ short lA[128 * 32];
  __shared__ short lB[128 * 32];
  const int t = threadIdx.x;
  const int lane = t & 63;
  const int wave = t >> 6;
  const int wr = (wave >> 1) * 64;   // wave row offset in tile
  const int wc = (wave & 1) * 64;    // wave col offset in tile
  const int tileM = blockIdx.y * 128;
  const int tileN = blockIdx.x * 128;

  f32x4 acc[4][4] = {};

  const short* aSrc = A  + (size_t)(tileM + (t >> 2)) * K + (t & 3) * 8;
  const short* bSrc = Bt + (size_t)(tileN + (t >> 2)) * K + (t & 3) * 8;
  const size_t rowStep = (size_t)64 * K;
  short* lAdst = lA + t * 8;   // linear: wave-uniform base + lane*16B
  short* lBdst = lB + t * 8;

  const int fr = lane & 15;
  const int kg = (lane >> 4) * 8;

  for (int k0 = 0; k0 < K; k0 += 32) {
    gload_lds16(aSrc + k0,           lAdst);
    gload_lds16(aSrc + rowStep + k0, lAdst + 64 * 32);
    gload_lds16(bSrc + k0,           lBdst);
    gload_lds16(bSrc + rowStep + k0, lBdst + 64 * 32);
    __syncthreads();
    short8 af[4], bf[4];
#pragma unroll
    for (int m = 0; m < 4; ++m)
      af[m] = *(const short8*)(lA + (wr + m * 16 + fr) * 32 + kg);
#pragma unroll
    for (int n = 0; n < 4; ++n)
      bf[n] = *(const short8*)(lB + (wc + n * 16 + fr) * 32 + kg);
#pragma unroll
    for (int m = 0; m < 4; ++m)
#pragma unroll
      for (int n = 0; n < 4; ++n)
        acc[m][n] = __builtin_amdgcn_mfma_f32_16x16x32_bf16(af[m], bf[n], acc[m][n], 0, 0, 0);
    __syncthreads();
  }

  // epilogue: C/D layout col=lane&15, row=(lane>>4)*4+reg  [m89-verified]
  const int rg = (lane >> 4) * 4;
#pragma unroll
  for (int m = 0; m < 4; ++m) {
#pragma unroll
    for (int n = 0; n < 4; ++n) {
      const int col = tileN + wc + n * 16 + fr;
      const float bi = BIAS ? bias[col] : 0.f;
      float sc = 1.f, sh = 0.f;
      if (BN) {
        sc = rsqrtf(var[col] + 1e-5f) * gamma[col];
        sh = beta[col] - mean[col] * sc;
      }
#pragma unroll
      for (int r = 0; r < 4; ++r) {
        const int row = tileM + wr + m * 16 + rg + r;
        float v = acc[m][n][r] + bi;
        if (BN) v = v * sc + sh;
        if (RELU) v = fmaxf(v, 0.f);
        C[(size_t)row * N + col] = f2bf(v);
      }
    }
  }
}

// ---------- conversions ----------
__global__ void conv_x_bf(const float* __restrict__ x, short* __restrict__ xb,
                          long nReal, long nTot) {
  long i = ((long)blockIdx.x * blockDim.x + threadIdx.x) * 4;
  if (i >= nTot) return;
  short4v o;
  if (i < nReal) {
    o[0] = f2bf(x[i + 0]); o[1] = f2bf(x[i + 1]);
    o[2] = f2bf(x[i + 2]); o[3] = f2bf(x[i + 3]);
  } else {
    o[0] = o[1] = o[2] = o[3] = 0;
  }
  *(short4v*)(xb + i) = o;
}

// all four weight transposes in one launch
__global__ void conv_w_all(const float* __restrict__ W1a, const float* __restrict__ W1b,
                           const float* __restrict__ W2a, const float* __restrict__ W2b,
                           short* __restrict__ W1aT, short* __restrict__ W1bT,
                           short* __restrict__ W2aT, short* __restrict__ W2bT,
                           int DIN, int DH) {
  int idx = blockIdx.x * blockDim.x + threadIdx.x;
  const int n1 = DIN * DH, n2 = DH * DH;
  if (idx < n1) {
    int k = idx / DH, n = idx - k * DH;
    W1aT[(size_t)n * DIN + k] = f2bf(W1a[idx]);
    return;
  }
  idx -= n1;
  if (idx >= 3 * n2) return;
  const int which = idx / n2;
  const int r = idx - which * n2;
  const int k = r / DH, n = r - k * DH;
  const float* W = (which == 0) ? W1b : (which == 1) ? W2a : W2b;
  short* T = (which == 0) ? W1bT : (which == 1) ? W2aT : W2bT;
  T[(size_t)n * DH + k] = f2bf(W[r]);
}

// ---------- CSR build ----------
__global__ void hist_deg(const int* __restrict__ dst, int* __restrict__ deg, int nE) {
  int e = blockIdx.x * blockDim.x + threadIdx.x;
  if (e < nE) atomicAdd(&deg[dst[e]], 1);
}

// single-block exclusive scan over n elements; writes rowstart[0..n] and cursor[0..n-1]
__global__ void scan_deg(const int* __restrict__ deg, int* __restrict__ rowstart,
                         int* __restrict__ cursor, int n) {
  __shared__ int wsum[16];
  __shared__ int carrySh;
  const int t = threadIdx.x;        // 1024 threads
  const int lane = t & 63, wv = t >> 6;
  int carry = 0;
  for (int base = 0; base < n; base += 8192) {
    int v[8]; int s = 0;
    const int i0 = base + t * 8;
#pragma unroll
    for (int j = 0; j < 8; ++j) {
      int idx = i0 + j;
      v[j] = (idx < n) ? deg[idx] : 0;
      s += v[j];
    }
    int ps = s;                      // inclusive wave scan
#pragma unroll
    for (int off = 1; off < 64; off <<= 1) {
      int u = __shfl_up(ps, off);
      if (lane >= off) ps += u;
    }
    if (lane == 63) wsum[wv] = ps;
    __syncthreads();
    if (wv == 0 && lane < 16) {
      int wsv = wsum[lane];
      int pw = wsv;
#pragma unroll
      for (int off = 1; off < 16; off <<= 1) {
        int u = __shfl_up(pw, off);
        if (lane >= off) pw += u;
      }
      wsum[lane] = pw - wsv;         // exclusive wave offset
      if (lane == 15) carrySh = pw;  // chunk total
    }
    __syncthreads();
    int run = carry + wsum[wv] + (ps - s);
#pragma unroll
    for (int j = 0; j < 8; ++j) {
      int idx = i0 + j;
      if (idx < n) { rowstart[idx] = run; cursor[idx] = run; }
      run += v[j];
    }
    carry += carrySh;
    __syncthreads();
  }
  if (t == 0) rowstart[n] = carry;
}

__global__ void fill_adj(const int* __restrict__ src, const int* __restrict__ dst,
                         int* __restrict__ cursor, int* __restrict__ adj, int nE) {
  int e = blockIdx.x * blockDim.x + threadIdx.x;
  if (e < nE) {
    int p = atomicAdd(&cursor[dst[e]], 1);
    adj[p] = src[e];
  }
}

// ---------- fused CSR aggregation + epilogue (bf16 in, f32 accum, bf16 out) ----------
// out_i = f( Y_i + sum_{j in adj(i)} Y_j )
// EPI 1: f = bf16(relu(BN(. + bias)))    EPI 0: f = bf16(.)
__device__ __forceinline__ void addbf8(f32x4& a0, f32x4& a1, short8 v) {
#pragma unroll
  for (int j = 0; j < 4; ++j) a0[j] += bf2f(v[j]);
#pragma unroll
  for (int j = 0; j < 4; ++j) a1[j] += bf2f(v[4 + j]);
}

template <int EPI>
__launch_bounds__(256)
__global__ void agg_csr(const short* __restrict__ Y,
                        const int* __restrict__ rowstart, const int* __restrict__ adj,
                        const float* __restrict__ bias, const float* __restrict__ gm,
                        const float* __restrict__ bt, const float* __restrict__ mn,
                        const float* __restrict__ vr,
                        short* __restrict__ out, int M) {
  const int node = blockIdx.x * 4 + (threadIdx.x >> 6);
  if (node >= M) return;
  const int lane = threadIdx.x & 63;
  const int d0 = lane * 8;

  f32x4 a0 = {}, a1 = {};
  addbf8(a0, a1, *(const short8*)(Y + (size_t)node * 512 + d0));  // self term

  int s = rowstart[node];
  const int e = rowstart[node + 1];
  while (s < e) {
    const int cnt = min(e - s, 64);
    int myn = (lane < cnt) ? adj[s + lane] : 0;
    int i = 0;
    for (; i + 3 < cnt; i += 4) {          // 4 gather loads in flight
      int n0 = __shfl(myn, i);
      int n1 = __shfl(myn, i + 1);
      int n2 = __shfl(myn, i + 2);
      int n3 = __shfl(myn, i + 3);
      short8 v0 = *(const short8*)(Y + (size_t)n0 * 512 + d0);
      short8 v1 = *(const short8*)(Y + (size_t)n1 * 512 + d0);
      short8 v2 = *(const short8*)(Y + (size_t)n2 * 512 + d0);
      short8 v3 = *(const short8*)(Y + (size_t)n3 * 512 + d0);
      addbf8(a0, a1, v0); addbf8(a0, a1, v1);
      addbf8(a0, a1, v2); addbf8(a0, a1, v3);
    }
    for (; i < cnt; ++i) {
      int n0 = __shfl(myn, i);
      addbf8(a0, a1, *(const short8*)(Y + (size_t)n0 * 512 + d0));
    }
    s += cnt;
  }

  short8 o;
#pragma unroll
  for (int j = 0; j < 8; ++j) {
    float val = (j < 4) ? a0[j] : a1[j - 4];
    if (EPI == 1) {
      const int d = d0 + j;
      float sc = rsqrtf(vr[d] + 1e-5f) * gm[d];
      float tv = (val + bias[d] - mn[d]) * sc + bt[d];
      o[j] = f2bf(fmaxf(tv, 0.f));
    } else {
      o[j] = f2bf(val);
    }
  }
  *(short8*)(out + (size_t)node * 512 + d0) = o;
}

// ---------- final projection [M,512] @ [512,2] + bout (bf16 H) ----------
__global__ void out_proj(const short* __restrict__ H, const float* __restrict__ Wout,
                         const float* __restrict__ bout, float* __restrict__ out, int M) {
  int row = blockIdx.x * 4 + (threadIdx.x >> 6);
  if (row >= M) return;
  int lane = threadIdx.x & 63;
  const short8 v = *(const short8*)(H + (size_t)row * 512 + lane * 8);
  float s0 = 0.f, s1 = 0.f;
#pragma unroll
  for (int j = 0; j < 8; ++j) {
    float h = bf2f(v[j]);
    s0 += h * Wout[(lane * 8 + j) * 2 + 0];
    s1 += h * Wout[(lane * 8 + j) * 2 + 1];
  }
#pragma unroll
  for (int off = 32; off > 0; off >>= 1) {
    s0 += __shfl_down(s0, off);
    s1 += __shfl_down(s1, off);
  }
  if (lane == 0) {
    out[row * 2 + 0] = s0 + bout[0];
    out[row * 2 + 1] = s1 + bout[1];
  }
}

extern "C" void kernel_launch(void* const* d_in, const int* in_sizes, int n_in,
                              void* d_out, int out_size, void* d_ws, size_t ws_size,
                              hipStream_t stream) {
  const float* x   = (const float*)d_in[0];
  const int*   ei  = (const int*)d_in[1];
  const float* W1a = (const float*)d_in[2];
  const float* b1a = (const float*)d_in[3];
  const float* g1  = (const float*)d_in[4];
  const float* be1 = (const float*)d_in[5];
  const float* m1  = (const float*)d_in[6];
  const float* v1  = (const float*)d_in[7];
  const float* W1b = (const float*)d_in[8];
  const float* b1b = (const float*)d_in[9];
  const float* W2a = (const float*)d_in[10];
  const float* b2a = (const float*)d_in[11];
  const float* g2  = (const float*)d_in[12];
  const float* be2 = (const float*)d_in[13];
  const float* m2  = (const float*)d_in[14];
  const float* v2  = (const float*)d_in[15];
  const float* W2b = (const float*)d_in[16];
  const float* b2b = (const float*)d_in[17];
  const float* Wo  = (const float*)d_in[18];
  const float* bo  = (const float*)d_in[19];

  const int DH   = in_sizes[3];            // 512
  const int DIN  = in_sizes[2] / DH;       // 768
  const int NN   = in_sizes[0] / DIN;      // 50000
  const int nE   = in_sizes[1] / 2;        // 500000
  const int Mpad = (NN + 127) & ~127;      // 50048

  char* ws = (char*)d_ws;
  short* XB = (short*)ws;                  // [Mpad,DIN] bf16
  size_t off = (size_t)Mpad * DIN * 2;
  short* W1aT = (short*)(ws + off); off += (size_t)DH * DIN * 2;
  short* W1bT = (short*)(ws + off); off += (size_t)DH * DH * 2;
  short* W2aT = (short*)(ws + off); off += (size_t)DH * DH * 2;
  short* W2bT = (short*)(ws + off); off += (size_t)DH * DH * 2;
  off = (off + 255) & ~(size_t)255;
  short* P = (short*)(ws + off); off += (size_t)Mpad * DH * 2;   // bf16 activations (ping)
  short* Q = (short*)(ws + off); off += (size_t)Mpad * DH * 2;   // bf16 activations (pong)
  off = (off + 255) & ~(size_t)255;
  int* deg      = (int*)(ws + off); off += (size_t)(Mpad + 1) * 4;
  int* rowstart = (int*)(ws + off); off += (size_t)(Mpad + 1) * 4;
  int* cursor   = (int*)(ws + off); off += (size_t)(Mpad + 1) * 4;
  int* adj      = (int*)(ws + off); off += (size_t)nE * 4;

  const int* srcI = ei;
  const int* dstI = ei + nE;

  const long nTot = (long)Mpad * DIN, nReal = (long)NN * DIN;

  // 0. dtype conversions + CSR build
  conv_x_bf<<<(int)((nTot / 4 + 255) / 256), 256, 0, stream>>>(x, XB, nReal, nTot);
  conv_w_all<<<(DIN * DH + 3 * DH * DH + 255) / 256, 256, 0, stream>>>(
      W1a, W1b, W2a, W2b, W1aT, W1bT, W2aT, W2bT, DIN, DH);
  hipMemsetAsync(deg, 0, (size_t)(Mpad + 1) * 4, stream);
  hist_deg<<<(nE + 255) / 256, 256, 0, stream>>>(dstI, deg, nE);
  scan_deg<<<1, 1024, 0, stream>>>(deg, rowstart, cursor, Mpad);
  fill_adj<<<(nE + 255) / 256, 256, 0, stream>>>(srcI, dstI, cursor, adj, nE);

  dim3 gg(DH / 128, Mpad / 128);
  const int aggGrid = Mpad / 4;

  // 1. Y1 = X @ W1a -> bf16 (no bias; aggregation commutes with the linear map)
  gemm_bt<false, false, false><<<gg, 256, 0, stream>>>(XB, W1aT, P, Mpad, DH, DIN,
                                                       nullptr, nullptr, nullptr, nullptr, nullptr);
  // 2. h1a = relu(BN(Y1_i + sum_j Y1_j + b1a)) -> bf16
  agg_csr<1><<<aggGrid, 256, 0, stream>>>(P, rowstart, adj, b1a, g1, be1, m1, v1, Q, Mpad);
  // 3. h1 = relu(h1a @ W1b + b1b) -> bf16
  gemm_bt<true, false, true><<<gg, 256, 0, stream>>>(Q, W1bT, P, Mpad, DH, DH,
                                                     b1b, nullptr, nullptr, nullptr, nullptr);
  // 4. h2pre = bf16(h1_i + sum_j h1_j)
  agg_csr<0><<<aggGrid, 256, 0, stream>>>(P, rowstart, adj, nullptr, nullptr, nullptr,
                                          nullptr, nullptr, Q, Mpad);
  // 5. h2a = relu(BN(h2pre @ W2a + b2a)) -> bf16
  gemm_bt<true, true, true><<<gg, 256, 0, stream>>>(Q, W2aT, P, Mpad, DH, DH,
                                                    b2a, g2, be2, m2, v2);
  // 6. h2 = relu(h2a @ W2b + b2b) -> bf16
  gemm_bt<true, false, true><<<gg, 256, 0, stream>>>(P, W2bT, Q, Mpad, DH, DH,
                                                     b2b, nullptr, nullptr, nullptr, nullptr);
  // 7. out = h2 @ Wout + bout
  out_proj<<<(NN + 3) / 4, 256, 0, stream>>>(Q, Wo, bo, (float*)d_out, NN);
}

// Round 9
// 781.039 us; speedup vs baseline: 2.8290x; 1.0148x over previous
//
#include <hip/hip_runtime.h>

typedef short short8  __attribute__((ext_vector_type(8)));
typedef short short4v __attribute__((ext_vector_type(4)));
typedef float f32x4   __attribute__((ext_vector_type(4)));

// ---------- helpers ----------
__device__ __forceinline__ short f2bf(float f) {
  union { float f; unsigned u; } v; v.f = f;
  unsigned r = v.u + 0x7fffu + ((v.u >> 16) & 1u);  // round-to-nearest-even
  return (short)(r >> 16);
}

__device__ __forceinline__ float bf2f(short s) {
  union { unsigned u; float f; } v;
  v.u = ((unsigned)(unsigned short)s) << 16;
  return v.f;
}

__device__ __forceinline__ void gload_lds16(const short* g, short* l) {
  __builtin_amdgcn_global_load_lds(
      (const __attribute__((address_space(1))) void*)g,
      (__attribute__((address_space(3))) void*)l, 16, 0, 0);
}

// ---------- bf16 MFMA GEMM: C[M,N] = A[M,K] @ B[K,N], B as Bt[N,K], bf16 out ----------
template <bool BIAS, bool BN, bool RELU>
__launch_bounds__(256)
__global__ void gemm_bt(const short* __restrict__ A, const short* __restrict__ Bt,
                        short* __restrict__ C, int Mpad, int N, int K,
                        const float* __restrict__ bias,
                        const float* __restrict__ gamma, const float* __restrict__ beta,
                        const float* __restrict__ mean, const float* __restrict__ var) {
  __shared__ short lA[128 * 32];
  __shared__ short lB[128 * 32];
  const int t = threadIdx.x;
  const int lane = t & 63;
  const int wave = t >> 6;
  const int wr = (wave >> 1) * 64;   // wave row offset in tile
  const int wc = (wave & 1) * 64;    // wave col offset in tile

  // bijective XCD-aware swizzle (m204): blocks sharing an A-row-tile (x fastest)
  // land on the same XCD's L2.
  const int nwgx = gridDim.x;
  const int nwg  = nwgx * gridDim.y;
  const int orig = blockIdx.y * nwgx + blockIdx.x;
  const int q = nwg >> 3, r = nwg & 7;
  const int xcd = orig & 7, sub = orig >> 3;
  const int swz = ((xcd < r) ? (xcd * (q + 1)) : (r * (q + 1) + (xcd - r) * q)) + sub;
  const int tileM = (swz / nwgx) * 128;
  const int tileN = (swz % nwgx) * 128;

  f32x4 acc[4][4] = {};

  const short* aSrc = A  + (size_t)(tileM + (t >> 2)) * K + (t & 3) * 8;
  const short* bSrc = Bt + (size_t)(tileN + (t >> 2)) * K + (t & 3) * 8;
  const size_t rowStep = (size_t)64 * K;
  short* lAdst = lA + t * 8;   // linear: wave-uniform base + lane*16B
  short* lBdst = lB + t * 8;

  const int fr = lane & 15;
  const int kg = (lane >> 4) * 8;

  for (int k0 = 0; k0 < K; k0 += 32) {
    gload_lds16(aSrc + k0,           lAdst);
    gload_lds16(aSrc + rowStep + k0, lAdst + 64 * 32);
    gload_lds16(bSrc + k0,           lBdst);
    gload_lds16(bSrc + rowStep + k0, lBdst + 64 * 32);
    __syncthreads();
    short8 af[4], bf[4];
#pragma unroll
    for (int m = 0; m < 4; ++m)
      af[m] = *(const short8*)(lA + (wr + m * 16 + fr) * 32 + kg);
#pragma unroll
    for (int n = 0; n < 4; ++n)
      bf[n] = *(const short8*)(lB + (wc + n * 16 + fr) * 32 + kg);
#pragma unroll
    for (int m = 0; m < 4; ++m)
#pragma unroll
      for (int n = 0; n < 4; ++n)
        acc[m][n] = __builtin_amdgcn_mfma_f32_16x16x32_bf16(af[m], bf[n], acc[m][n], 0, 0, 0);
    __syncthreads();
  }

  // epilogue: C/D layout col=lane&15, row=(lane>>4)*4+reg  [m89-verified]
  const int rg = (lane >> 4) * 4;
#pragma unroll
  for (int m = 0; m < 4; ++m) {
#pragma unroll
    for (int n = 0; n < 4; ++n) {
      const int col = tileN + wc + n * 16 + fr;
      const float bi = BIAS ? bias[col] : 0.f;
      float sc = 1.f, sh = 0.f;
      if (BN) {
        sc = rsqrtf(var[col] + 1e-5f) * gamma[col];
        sh = beta[col] - mean[col] * sc;
      }
#pragma unroll
      for (int r2 = 0; r2 < 4; ++r2) {
        const int row = tileM + wr + m * 16 + rg + r2;
        float v = acc[m][n][r2] + bi;
        if (BN) v = v * sc + sh;
        if (RELU) v = fmaxf(v, 0.f);
        C[(size_t)row * N + col] = f2bf(v);
      }
    }
  }
}

// ---------- conversions ----------
__global__ void conv_x_bf(const float* __restrict__ x, short* __restrict__ xb,
                          long nReal, long nTot) {
  long i = ((long)blockIdx.x * blockDim.x + threadIdx.x) * 4;
  if (i >= nTot) return;
  short4v o;
  if (i < nReal) {
    o[0] = f2bf(x[i + 0]); o[1] = f2bf(x[i + 1]);
    o[2] = f2bf(x[i + 2]); o[3] = f2bf(x[i + 3]);
  } else {
    o[0] = o[1] = o[2] = o[3] = 0;
  }
  *(short4v*)(xb + i) = o;
}

// all four weight transposes in one launch
__global__ void conv_w_all(const float* __restrict__ W1a, const float* __restrict__ W1b,
                           const float* __restrict__ W2a, const float* __restrict__ W2b,
                           short* __restrict__ W1aT, short* __restrict__ W1bT,
                           short* __restrict__ W2aT, short* __restrict__ W2bT,
                           int DIN, int DH) {
  int idx = blockIdx.x * blockDim.x + threadIdx.x;
  const int n1 = DIN * DH, n2 = DH * DH;
  if (idx < n1) {
    int k = idx / DH, n = idx - k * DH;
    W1aT[(size_t)n * DIN + k] = f2bf(W1a[idx]);
    return;
  }
  idx -= n1;
  if (idx >= 3 * n2) return;
  const int which = idx / n2;
  const int r = idx - which * n2;
  const int k = r / DH, n = r - k * DH;
  const float* W = (which == 0) ? W1b : (which == 1) ? W2a : W2b;
  short* T = (which == 0) ? W1bT : (which == 1) ? W2aT : W2bT;
  T[(size_t)n * DH + k] = f2bf(W[r]);
}

// ---------- CSR build ----------
__global__ void hist_deg(const int* __restrict__ dst, int* __restrict__ deg, int nE) {
  int e = blockIdx.x * blockDim.x + threadIdx.x;
  if (e < nE) atomicAdd(&deg[dst[e]], 1);
}

// single-block exclusive scan over n elements; writes rowstart[0..n] and cursor[0..n-1]
__global__ void scan_deg(const int* __restrict__ deg, int* __restrict__ rowstart,
                         int* __restrict__ cursor, int n) {
  __shared__ int wsum[16];
  __shared__ int carrySh;
  const int t = threadIdx.x;        // 1024 threads
  const int lane = t & 63, wv = t >> 6;
  int carry = 0;
  for (int base = 0; base < n; base += 8192) {
    int v[8]; int s = 0;
    const int i0 = base + t * 8;
#pragma unroll
    for (int j = 0; j < 8; ++j) {
      int idx = i0 + j;
      v[j] = (idx < n) ? deg[idx] : 0;
      s += v[j];
    }
    int ps = s;                      // inclusive wave scan
#pragma unroll
    for (int off = 1; off < 64; off <<= 1) {
      int u = __shfl_up(ps, off);
      if (lane >= off) ps += u;
    }
    if (lane == 63) wsum[wv] = ps;
    __syncthreads();
    if (wv == 0 && lane < 16) {
      int wsv = wsum[lane];
      int pw = wsv;
#pragma unroll
      for (int off = 1; off < 16; off <<= 1) {
        int u = __shfl_up(pw, off);
        if (lane >= off) pw += u;
      }
      wsum[lane] = pw - wsv;         // exclusive wave offset
      if (lane == 15) carrySh = pw;  // chunk total
    }
    __syncthreads();
    int run = carry + wsum[wv] + (ps - s);
#pragma unroll
    for (int j = 0; j < 8; ++j) {
      int idx = i0 + j;
      if (idx < n) { rowstart[idx] = run; cursor[idx] = run; }
      run += v[j];
    }
    carry += carrySh;
    __syncthreads();
  }
  if (t == 0) rowstart[n] = carry;
}

__global__ void fill_adj(const int* __restrict__ src, const int* __restrict__ dst,
                         int* __restrict__ cursor, int* __restrict__ adj, int nE) {
  int e = blockIdx.x * blockDim.x + threadIdx.x;
  if (e < nE) {
    int p = atomicAdd(&cursor[dst[e]], 1);
    adj[p] = src[e];
  }
}

// ---------- fused CSR aggregation + epilogue (bf16 in, f32 accum, bf16 out) ----------
// out_i = f( Y_i + sum_{j in adj(i)} Y_j )
// EPI 1: f = bf16(relu(BN(. + bias)))    EPI 0: f = bf16(.)
__device__ __forceinline__ void addbf8(f32x4& a0, f32x4& a1, short8 v) {
#pragma unroll
  for (int j = 0; j < 4; ++j) a0[j] += bf2f(v[j]);
#pragma unroll
  for (int j = 0; j < 4; ++j) a1[j] += bf2f(v[4 + j]);
}

template <int EPI>
__launch_bounds__(256)
__global__ void agg_csr(const short* __restrict__ Y,
                        const int* __restrict__ rowstart, const int* __restrict__ adj,
                        const float* __restrict__ bias, const float* __restrict__ gm,
                        const float* __restrict__ bt, const float* __restrict__ mn,
                        const float* __restrict__ vr,
                        short* __restrict__ out, int M) {
  const int node = blockIdx.x * 4 + (threadIdx.x >> 6);
  if (node >= M) return;
  const int lane = threadIdx.x & 63;
  const int d0 = lane * 8;

  f32x4 a0 = {}, a1 = {};
  addbf8(a0, a1, *(const short8*)(Y + (size_t)node * 512 + d0));  // self term

  int s = rowstart[node];
  const int e = rowstart[node + 1];
  while (s < e) {
    const int cnt = min(e - s, 64);
    int myn = (lane < cnt) ? adj[s + lane] : 0;
    int i = 0;
    for (; i + 7 < cnt; i += 8) {          // 8 gather loads in flight
      short8 v0 = *(const short8*)(Y + (size_t)__shfl(myn, i + 0) * 512 + d0);
      short8 v1 = *(const short8*)(Y + (size_t)__shfl(myn, i + 1) * 512 + d0);
      short8 v2 = *(const short8*)(Y + (size_t)__shfl(myn, i + 2) * 512 + d0);
      short8 v3 = *(const short8*)(Y + (size_t)__shfl(myn, i + 3) * 512 + d0);
      short8 v4 = *(const short8*)(Y + (size_t)__shfl(myn, i + 4) * 512 + d0);
      short8 v5 = *(const short8*)(Y + (size_t)__shfl(myn, i + 5) * 512 + d0);
      short8 v6 = *(const short8*)(Y + (size_t)__shfl(myn, i + 6) * 512 + d0);
      short8 v7 = *(const short8*)(Y + (size_t)__shfl(myn, i + 7) * 512 + d0);
      addbf8(a0, a1, v0); addbf8(a0, a1, v1);
      addbf8(a0, a1, v2); addbf8(a0, a1, v3);
      addbf8(a0, a1, v4); addbf8(a0, a1, v5);
      addbf8(a0, a1, v6); addbf8(a0, a1, v7);
    }
    for (; i < cnt; ++i) {
      int n0 = __shfl(myn, i);
      addbf8(a0, a1, *(const short8*)(Y + (size_t)n0 * 512 + d0));
    }
    s += cnt;
  }

  short8 o;
#pragma unroll
  for (int j = 0; j < 8; ++j) {
    float val = (j < 4) ? a0[j] : a1[j - 4];
    if (EPI == 1) {
      const int d = d0 + j;
      float sc = rsqrtf(vr[d] + 1e-5f) * gm[d];
      float tv = (val + bias[d] - mn[d]) * sc + bt[d];
      o[j] = f2bf(fmaxf(tv, 0.f));
    } else {
      o[j] = f2bf(val);
    }
  }
  *(short8*)(out + (size_t)node * 512 + d0) = o;
}

// ---------- final projection [M,512] @ [512,2] + bout (bf16 H) ----------
__global__ void out_proj(const short* __restrict__ H, const float* __restrict__ Wout,
                         const float* __restrict__ bout, float* __restrict__ out, int M) {
  int row = blockIdx.x * 4 + (threadIdx.x >> 6);
  if (row >= M) return;
  int lane = threadIdx.x & 63;
  const short8 v = *(const short8*)(H + (size_t)row * 512 + lane * 8);
  float s0 = 0.f, s1 = 0.f;
#pragma unroll
  for (int j = 0; j < 8; ++j) {
    float h = bf2f(v[j]);
    s0 += h * Wout[(lane * 8 + j) * 2 + 0];
    s1 += h * Wout[(lane * 8 + j) * 2 + 1];
  }
#pragma unroll
  for (int off = 32; off > 0; off >>= 1) {
    s0 += __shfl_down(s0, off);
    s1 += __shfl_down(s1, off);
  }
  if (lane == 0) {
    out[row * 2 + 0] = s0 + bout[0];
    out[row * 2 + 1] = s1 + bout[1];
  }
}

extern "C" void kernel_launch(void* const* d_in, const int* in_sizes, int n_in,
                              void* d_out, int out_size, void* d_ws, size_t ws_size,
                              hipStream_t stream) {
  const float* x   = (const float*)d_in[0];
  const int*   ei  = (const int*)d_in[1];
  const float* W1a = (const float*)d_in[2];
  const float* b1a = (const float*)d_in[3];
  const float* g1  = (const float*)d_in[4];
  const float* be1 = (const float*)d_in[5];
  const float* m1  = (const float*)d_in[6];
  const float* v1  = (const float*)d_in[7];
  const float* W1b = (const float*)d_in[8];
  const float* b1b = (const float*)d_in[9];
  const float* W2a = (const float*)d_in[10];
  const float* b2a = (const float*)d_in[11];
  const float* g2  = (const float*)d_in[12];
  const float* be2 = (const float*)d_in[13];
  const float* m2  = (const float*)d_in[14];
  const float* v2  = (const float*)d_in[15];
  const float* W2b = (const float*)d_in[16];
  const float* b2b = (const float*)d_in[17];
  const float* Wo  = (const float*)d_in[18];
  const float* bo  = (const float*)d_in[19];

  const int DH   = in_sizes[3];            // 512
  const int DIN  = in_sizes[2] / DH;       // 768
  const int NN   = in_sizes[0] / DIN;      // 50000
  const int nE   = in_sizes[1] / 2;        // 500000
  const int Mpad = (NN + 127) & ~127;      // 50048

  char* ws = (char*)d_ws;
  short* XB = (short*)ws;                  // [Mpad,DIN] bf16
  size_t off = (size_t)Mpad * DIN * 2;
  short* W1aT = (short*)(ws + off); off += (size_t)DH * DIN * 2;
  short* W1bT = (short*)(ws + off); off += (size_t)DH * DH * 2;
  short* W2aT = (short*)(ws + off); off += (size_t)DH * DH * 2;
  short* W2bT = (short*)(ws + off); off += (size_t)DH * DH * 2;
  off = (off + 255) & ~(size_t)255;
  short* P = (short*)(ws + off); off += (size_t)Mpad * DH * 2;   // bf16 activations (ping)
  short* Q = (short*)(ws + off); off += (size_t)Mpad * DH * 2;   // bf16 activations (pong)
  off = (off + 255) & ~(size_t)255;
  int* deg      = (int*)(ws + off); off += (size_t)(Mpad + 1) * 4;
  int* rowstart = (int*)(ws + off); off += (size_t)(Mpad + 1) * 4;
  int* cursor   = (int*)(ws + off); off += (size_t)(Mpad + 1) * 4;
  int* adj      = (int*)(ws + off); off += (size_t)nE * 4;

  const int* srcI = ei;
  const int* dstI = ei + nE;

  const long nTot = (long)Mpad * DIN, nReal = (long)NN * DIN;

  // 0. dtype conversions + CSR build
  conv_x_bf<<<(int)((nTot / 4 + 255) / 256), 256, 0, stream>>>(x, XB, nReal, nTot);
  conv_w_all<<<(DIN * DH + 3 * DH * DH + 255) / 256, 256, 0, stream>>>(
      W1a, W1b, W2a, W2b, W1aT, W1bT, W2aT, W2bT, DIN, DH);
  hipMemsetAsync(deg, 0, (size_t)(Mpad + 1) * 4, stream);
  hist_deg<<<(nE + 255) / 256, 256, 0, stream>>>(dstI, deg, nE);
  scan_deg<<<1, 1024, 0, stream>>>(deg, rowstart, cursor, Mpad);
  fill_adj<<<(nE + 255) / 256, 256, 0, stream>>>(srcI, dstI, cursor, adj, nE);

  dim3 gg(DH / 128, Mpad / 128);
  const int aggGrid = Mpad / 4;

  // 1. Y1 = X @ W1a -> bf16 (no bias; aggregation commutes with the linear map)
  gemm_bt<false, false, false><<<gg, 256, 0, stream>>>(XB, W1aT, P, Mpad, DH, DIN,
                                                       nullptr, nullptr, nullptr, nullptr, nullptr);
  // 2. h1a = relu(BN(Y1_i + sum_j Y1_j + b1a)) -> bf16
  agg_csr<1><<<aggGrid, 256, 0, stream>>>(P, rowstart, adj, b1a, g1, be1, m1, v1, Q, Mpad);
  // 3. h1 = relu(h1a @ W1b + b1b) -> bf16
  gemm_bt<true, false, true><<<gg, 256, 0, stream>>>(Q, W1bT, P, Mpad, DH, DH,
                                                     b1b, nullptr, nullptr, nullptr, nullptr);
  // 4. h2pre = bf16(h1_i + sum_j h1_j)
  agg_csr<0><<<aggGrid, 256, 0, stream>>>(P, rowstart, adj, nullptr, nullptr, nullptr,
                                          nullptr, nullptr, Q, Mpad);
  // 5. h2a = relu(BN(h2pre @ W2a + b2a)) -> bf16
  gemm_bt<true, true, true><<<gg, 256, 0, stream>>>(Q, W2aT, P, Mpad, DH, DH,
                                                    b2a, g2, be2, m2, v2);
  // 6. h2 = relu(h2a @ W2b + b2b) -> bf16
  gemm_bt<true, false, true><<<gg, 256, 0, stream>>>(P, W2bT, Q, Mpad, DH, DH,
                                                     b2b, nullptr, nullptr, nullptr, nullptr);
  // 7. out = h2 @ Wout + bout
  out_proj<<<(NN + 3) / 4, 256, 0, stream>>>(Q, Wo, bo, (float*)d_out, NN);
}